// Round 13
// baseline (50.785 us; speedup 1.0000x reference)
//
#include <hip/hip_runtime.h>
#include <cstdint>

namespace {

constexpr int NB = 320;   // batch
constexpr int ND = 128;   // feature dim
constexpr int NC = 80;    // label dim
constexpr int NANCH = 30;
constexpr int NW = 5;     // 64-bit words per 320-bit row
constexpr int APB = 8;    // anchors per block
constexpr int NBLK = NB / APB;   // 40 blocks

// ---- workspace layout (byte offsets) ----
constexpr size_t OFF_DIV  = 0;        // float[320]
constexpr size_t OFF_ASUM = 1280;     // double[320]
constexpr size_t OFF_ACNT = 3840;     // int[320]
constexpr size_t OFF_PACK = 5120;     // u64[640]
constexpr size_t OFF_TGTT = 10240;    // float2[64][320] = 163840 B

// K0: transpose tgt + pack labels (verbatim from the R10 31.3us lineage).
__global__ __launch_bounds__(256) void k_prep(
    const float* __restrict__ tgt,
    const int* __restrict__ label,
    float2* __restrict__ tgtT2,
    unsigned long long* __restrict__ packed)
{
    const int tid = threadIdx.x;
    const int w = tid >> 6, lane = tid & 63;
    const int r0 = blockIdx.x * 64;            // 5 blocks x 64 rows

    __shared__ float tile[64][133];

    if (w == 0) {
        const int r = r0 + lane;
        const int4* lp = reinterpret_cast<const int4*>(label + r * NC);
        unsigned long long j0 = 0, j1 = 0;
#pragma unroll
        for (int q = 0; q < 16; ++q) {
            int4 v = lp[q];
            j0 |= (unsigned long long)(v.x != 0) << (4 * q + 0);
            j0 |= (unsigned long long)(v.y != 0) << (4 * q + 1);
            j0 |= (unsigned long long)(v.z != 0) << (4 * q + 2);
            j0 |= (unsigned long long)(v.w != 0) << (4 * q + 3);
        }
#pragma unroll
        for (int q = 16; q < 20; ++q) {
            int4 v = lp[q];
            const int b = 4 * (q - 16);
            j1 |= (unsigned long long)(v.x != 0) << (b + 0);
            j1 |= (unsigned long long)(v.y != 0) << (b + 1);
            j1 |= (unsigned long long)(v.z != 0) << (b + 2);
            j1 |= (unsigned long long)(v.w != 0) << (b + 3);
        }
        packed[2 * r]     = j0;
        packed[2 * r + 1] = j1;
    }

#pragma unroll
    for (int it = 0; it < 8; ++it) {
        const int f4 = it * 256 + tid;
        float4 v = reinterpret_cast<const float4*>(tgt)[r0 * (ND / 4) + f4];
        const int r = f4 >> 5, d4 = (f4 & 31) << 2;
        tile[r][d4 + 0] = v.x; tile[r][d4 + 1] = v.y;
        tile[r][d4 + 2] = v.z; tile[r][d4 + 3] = v.w;
    }
    __syncthreads();

#pragma unroll
    for (int it = 0; it < 16; ++it) {
        const int d2 = it * 4 + w;
        float2 o;
        o.x = tile[lane][2 * d2 + 0];
        o.y = tile[lane][2 * d2 + 1];
        tgtT2[d2 * NB + r0 + lane] = o;
    }
}

// K1: 40 blocks x 8 anchors. Each tgtT2 column value is loaded once per
// thread and feeds 8 dot accumulators (d-outer / anchor-inner). Every
// per-anchor FP reduction reproduces the ORIGINAL 256-thread mapping of the
// absmax-0.0 lineage: d-sequential dot expression, red-tree for divr, ballot
// masks (integer-exact), original jj/wave/wsum triplet order.
__global__ __launch_bounds__(256) void k_fd8(
    const float* __restrict__ src,
    const float2* __restrict__ tgtT2,
    const unsigned long long* __restrict__ packed,
    float* __restrict__ divr,
    double* __restrict__ asum,
    int* __restrict__ acnt)
{
    const int a0 = blockIdx.x * APB;
    const int tid = threadIdx.x;
    const int w = tid >> 6, lane = tid & 63;

    __shared__ float sa8[APB][ND];              // 4 KB
    __shared__ float nsa8[APB];
    __shared__ unsigned long long pk[2 * NB];   // 5 KB
    __shared__ float fdrow8[APB][NB];           // 10 KB
    __shared__ float red8[APB][256];            // 8 KB
    __shared__ unsigned long long pm8[APB][NW], nm8[APB][NW];
    __shared__ double wsum8[APB][4];

    // stage the 8 src rows (1024 floats; one float4 per thread, coalesced)
    {
        const int ai = tid >> 5;                // (4*tid)/128
        const int d  = (tid & 31) << 2;
        *reinterpret_cast<float4*>(&sa8[ai][d]) =
            *reinterpret_cast<const float4*>(&src[(a0 + ai) * ND + d]);
    }
    // src norms: wave w handles anchors {w, w+4}; original shfl tree per anchor
    for (int ai = w; ai < APB; ai += 4) {
        float s0 = src[(a0 + ai) * ND + lane];
        float s1 = src[(a0 + ai) * ND + lane + 64];
        float v = s0 * s0 + s1 * s1;
        for (int off = 32; off > 0; off >>= 1) v += __shfl_down(v, off);
        if (lane == 0) nsa8[ai] = sqrtf(v);
    }
    for (int q = tid; q < 2 * NB; q += 256) pk[q] = packed[q];
    __syncthreads();

    // ---- fd: thread t owns column j; 8 anchors share each loaded value ----
#pragma unroll
    for (int it = 0; it < 2; ++it) {
        const int j = tid + 256 * it;           // it=1: wave 0 only (uniform)
        if (j < NB) {
            float dot[APB];
#pragma unroll
            for (int ai = 0; ai < APB; ++ai) dot[ai] = 0.f;
            float tn = 0.f;
#pragma unroll
            for (int d4 = 0; d4 < ND / 4; ++d4) {
                float2 u = tgtT2[(2 * d4 + 0) * NB + j];
                float2 v = tgtT2[(2 * d4 + 1) * NB + j];
#pragma unroll
                for (int ai = 0; ai < APB; ++ai) {
                    float4 s = *reinterpret_cast<const float4*>(&sa8[ai][4 * d4]);
                    dot[ai] += s.x * u.x + s.y * u.y + s.z * v.x + s.w * v.y;
                }
                tn += u.x * u.x + u.y * u.y + v.x * v.x + v.y * v.y;
            }
            const float st = sqrtf(tn);
#pragma unroll
            for (int ai = 0; ai < APB; ++ai) {
                float sim = dot[ai] / fmaxf(nsa8[ai] * st, 1e-8f);
                fdrow8[ai][j] = fmaxf(1.0f - sim, 0.0f);
            }
        }
    }
    __syncthreads();

    // ---- divr: original red-tree, 8 anchors per barrier step ----
#pragma unroll
    for (int ai = 0; ai < APB; ++ai)
        red8[ai][tid] = (tid < 64) ? fdrow8[ai][tid] + fdrow8[ai][tid + 256]
                                   : fdrow8[ai][tid];
    __syncthreads();
    for (int st = 128; st > 0; st >>= 1) {
        if (tid < st) {
#pragma unroll
            for (int ai = 0; ai < APB; ++ai)
                red8[ai][tid] += red8[ai][tid + st];
        }
        __syncthreads();
    }
    if (tid < APB) divr[a0 + tid] = red8[tid][0] / (float)NB;

    // ---- classification: integer-exact, original ballot mapping ----
#pragma unroll 1
    for (int ai = 0; ai < APB; ++ai) {
        const int a = a0 + ai;
        const unsigned long long A0 = pk[2 * a], A1 = pk[2 * a + 1];
        const float sna = sqrtf((float)(__popcll(A0) + __popcll(A1)));
#pragma unroll
        for (int it = 0; it < 2; ++it) {
            const int jj = tid + 256 * it;
            if (jj < NB) {
                const unsigned long long j0 = pk[2 * jj], j1 = pk[2 * jj + 1];
                const float snj = sqrtf((float)(__popcll(j0) + __popcll(j1)));
                const float denom = sna * snj;
                const float dotf = (float)(__popcll(A0 & j0) + __popcll(A1 & j1));
                const float ld = 1.0f - fminf(1.0f, dotf / denom);
                const bool valid = (jj != a) && (denom > 0.f); // 0-label -> NaN in ref -> excluded
                unsigned long long pb = __ballot(valid && (ld <= 0.2f));
                unsigned long long nb = __ballot(valid && (ld >= 0.5f));
                if (lane == 0) { pm8[ai][jj >> 6] = pb; nm8[ai][jj >> 6] = nb; }
            }
        }
    }
    __syncthreads();

    // ---- triplet sums: original jj/wave/wsum order per anchor ----
#pragma unroll 1
    for (int ai = 0; ai < APB; ++ai) {
        double s = 0.0;
#pragma unroll
        for (int it = 0; it < 2; ++it) {
            const int jj = tid + 256 * it;
            if (jj < NB && ((nm8[ai][jj >> 6] >> (jj & 63)) & 1ull)) {
                const float fn = fdrow8[ai][jj];
#pragma unroll
                for (int wd = 0; wd < NW; ++wd) {
                    unsigned long long m = pm8[ai][wd];
                    while (m) {
                        const int b = __builtin_ctzll(m);
                        m &= m - 1;
                        float v = fdrow8[ai][wd * 64 + b] - fn + 0.5f;
                        if (v > 0.f) s += (double)v;
                    }
                }
            }
        }
        for (int off = 32; off > 0; off >>= 1) s += __shfl_down(s, off);
        if (lane == 0) wsum8[ai][w] = s;
    }
    __syncthreads();
    if (tid < APB) {
        int P = 0, N = 0;
#pragma unroll
        for (int wd = 0; wd < NW; ++wd) {
            P += __popcll(pm8[tid][wd]);
            N += __popcll(nm8[tid][wd]);
        }
        asum[a0 + tid] = wsum8[tid][0] + wsum8[tid][1] + wsum8[tid][2] + wsum8[tid][3];
        acnt[a0 + tid] = P * N;
    }
}

// K2: tiny tail -- rank-based top-30, gather precomputed (sum, count), divide.
__global__ __launch_bounds__(320) void k_final(
    const float* __restrict__ divr,
    const double* __restrict__ asum,
    const int* __restrict__ acnt,
    float* __restrict__ out)
{
    const int tid = threadIdx.x;
    __shared__ float dv[NB];
    __shared__ int alist[NANCH];
    __shared__ double sl[NANCH];
    __shared__ int cl[NANCH];

    dv[tid] = divr[tid];
    __syncthreads();

    const float ve = dv[tid];
    int rank = 0;
#pragma unroll 8
    for (int j = 0; j < NB; ++j) {
        float vj = dv[j];
        rank += (vj > ve) || (vj == ve && j < tid);
    }
    if (rank < NANCH) alist[rank] = tid;   // ranks unique; = lax.top_k order
    __syncthreads();

    if (tid < NANCH) {
        sl[tid] = asum[alist[tid]];
        cl[tid] = acnt[alist[tid]];
    }
    __syncthreads();
    if (tid == 0) {
        double S = 0.0;
        long long C = 0;
        for (int r = 0; r < NANCH; ++r) { S += sl[r]; C += cl[r]; }
        out[0] = (float)(S / ((double)C + 1e-4));
    }
}

} // namespace

extern "C" void kernel_launch(void* const* d_in, const int* in_sizes, int n_in,
                              void* d_out, int out_size, void* d_ws, size_t ws_size,
                              hipStream_t stream) {
    const int* label = (const int*)d_in[0];
    const float* src = (const float*)d_in[1];
    const float* tgt = (const float*)d_in[2];

    char* ws = (char*)d_ws;
    float* divr  = (float*)(ws + OFF_DIV);
    double* asum = (double*)(ws + OFF_ASUM);
    int* acnt    = (int*)(ws + OFF_ACNT);
    unsigned long long* packed = (unsigned long long*)(ws + OFF_PACK);
    float2* tgtT2 = (float2*)(ws + OFF_TGTT);

    k_prep <<<5, 256, 0, stream>>>(tgt, label, tgtT2, packed);
    k_fd8  <<<NBLK, 256, 0, stream>>>(src, tgtT2, packed, divr, asum, acnt);
    k_final<<<1, 320, 0, stream>>>(divr, asum, acnt, (float*)d_out);
}